// Round 2
// baseline (340.347 us; speedup 1.0000x reference)
//
#include <hip/hip_runtime.h>
#include <hip/hip_bf16.h>

// B=2, S=2048, D_MODEL=1024, H=16, D_HEAD=64. I/O: float32 (per reference).
// Internal intermediates bf16. Pipeline:
//   Wt = bf16(transpose(W)) x4 -> ws
//   qm = bf16(q@Wq+bq) [4096,1024], km likewise, vt = bf16((kv@Wv+bv))^T per head [B,H,64,S]
//   attn = flash-attention(qm,km,vt) merged heads [4096,1024] bf16
//   om = bf16(attn@Wo+bo)
//   out = f32 LayerNorm(q+om)*gamma+beta

#define DM 1024
#define SEQ 2048
#define NB 2
#define NH 16
#define DH 64

typedef __attribute__((ext_vector_type(8))) short bf16x8;
typedef __attribute__((ext_vector_type(4))) float f32x4;

__device__ __forceinline__ float bf2f(short s) {
  unsigned u = ((unsigned)(unsigned short)s) << 16;
  return __builtin_bit_cast(float, u);
}
__device__ __forceinline__ short f2bf(float f) {
  unsigned u = __builtin_bit_cast(unsigned, f);
  u += 0x7fffu + ((u >> 16) & 1u);  // RNE
  return (short)(u >> 16);
}
__device__ __forceinline__ bf16x8 cvt8(const float4 a, const float4 b) {
  bf16x8 r;
  r[0] = f2bf(a.x); r[1] = f2bf(a.y); r[2] = f2bf(a.z); r[3] = f2bf(a.w);
  r[4] = f2bf(b.x); r[5] = f2bf(b.y); r[6] = f2bf(b.z); r[7] = f2bf(b.w);
  return r;
}

#define GLL16(gsrc, ldst)                                                     \
  __builtin_amdgcn_global_load_lds(                                           \
      (const __attribute__((address_space(1))) void*)(gsrc),                  \
      (__attribute__((address_space(3))) void*)(ldst), 16, 0, 0)

// ---------------------------------------------------------------- transpose
// W f32 [k][n] -> Wt bf16 [n][k]
__global__ __launch_bounds__(256) void k_transpose(
    const float* __restrict__ Wq, const float* __restrict__ Wk,
    const float* __restrict__ Wv, const float* __restrict__ Wo,
    short* __restrict__ Wt_all) {
  const int z = blockIdx.z;
  const float* src = (z == 0) ? Wq : (z == 1) ? Wk : (z == 2) ? Wv : Wo;
  short* dst = Wt_all + (size_t)z * (DM * DM);
  __shared__ float t[32][33];
  const int n0 = blockIdx.x * 32, k0 = blockIdx.y * 32;
  const int tx = threadIdx.x, ty = threadIdx.y;  // (32,8)
#pragma unroll
  for (int i = 0; i < 32; i += 8)
    t[ty + i][tx] = src[(size_t)(k0 + ty + i) * DM + n0 + tx];
  __syncthreads();
#pragma unroll
  for (int i = 0; i < 32; i += 8)
    dst[(size_t)(n0 + ty + i) * DM + k0 + tx] = f2bf(t[tx][ty + i]);
}

// ---------------------------------------------------------------- GEMM body
// C[m,n] = sum_k A[m,k]*Wt[n,k] + bias[n]; M=4096, N=K=1024.
// 128x128 tile, BK=32, 4 waves, each wave 64x64 (4x4 frags of 16x16x32).
// A_F32: A read from f32 global, reg-staged + converted; else bf16 via GLL16.
template <int A_F32>
__device__ __forceinline__ void gemm_body(short* As, short* Bs,
                                          const float* __restrict__ Xf,
                                          const short* __restrict__ Xb,
                                          const short* __restrict__ Wt,
                                          const float* __restrict__ bias,
                                          short* __restrict__ out,
                                          int vt_mode) {
  const int tid = threadIdx.x;
  const int w = tid >> 6, l = tid & 63;
  const int g = l >> 4, qi = l & 15;
  const int n0 = blockIdx.x * 128;
  const int m0 = blockIdx.y * 128;
  const int wr = w >> 1, wc = w & 1;

  f32x4 acc[4][4];
#pragma unroll
  for (int m = 0; m < 4; m++)
#pragma unroll
    for (int n = 0; n < 4; n++) acc[m][n] = (f32x4){0.f, 0.f, 0.f, 0.f};

  // staging map: row = i*64 + w*16 + (l>>2), col = (l&3)*8 ; LDS short idx =
  // i*2048 + w*512 + l*8  (linear, matches global_load_lds lane order)
  const int srow = w * 16 + (l >> 2);
  const int scol = (l & 3) * 8;
  const float* Agf = A_F32 ? (Xf + (size_t)(m0 + srow) * DM + scol) : nullptr;
  const short* Agb = A_F32 ? nullptr : (Xb + (size_t)(m0 + srow) * DM + scol);
  const short* Bg = Wt + (size_t)(n0 + srow) * DM + scol;

  for (int k0 = 0; k0 < DM; k0 += 32) {
    float4 a0, a1, a2, a3;
    if (A_F32) {
      const float* p0 = Agf + k0;
      const float* p1 = Agf + (size_t)64 * DM + k0;
      a0 = *(const float4*)(p0);
      a1 = *(const float4*)(p0 + 4);
      a2 = *(const float4*)(p1);
      a3 = *(const float4*)(p1 + 4);
    }
    __syncthreads();
    if (A_F32) {
      *(bf16x8*)&As[w * 512 + l * 8] = cvt8(a0, a1);
      *(bf16x8*)&As[2048 + w * 512 + l * 8] = cvt8(a2, a3);
    } else {
#pragma unroll
      for (int i = 0; i < 2; i++)
        GLL16(Agb + (size_t)i * 64 * DM + k0, As + w * 512 + i * 2048);
    }
#pragma unroll
    for (int i = 0; i < 2; i++)
      GLL16(Bg + (size_t)i * 64 * DM + k0, Bs + w * 512 + i * 2048);
    __syncthreads();

    bf16x8 a[4], b[4];
#pragma unroll
    for (int m = 0; m < 4; m++)
      a[m] = *(const bf16x8*)&As[(wr * 64 + m * 16 + qi) * 32 + 8 * g];
#pragma unroll
    for (int n = 0; n < 4; n++)
      b[n] = *(const bf16x8*)&Bs[(wc * 64 + n * 16 + qi) * 32 + 8 * g];
#pragma unroll
    for (int m = 0; m < 4; m++)
#pragma unroll
      for (int n = 0; n < 4; n++)
        acc[m][n] =
            __builtin_amdgcn_mfma_f32_16x16x32_bf16(a[m], b[n], acc[m][n], 0, 0, 0);
  }

  const int col0 = n0 + wc * 64;
  const int row0 = m0 + wr * 64;
  float bfv[4];
#pragma unroll
  for (int n = 0; n < 4; n++) bfv[n] = bias[col0 + n * 16 + qi];

  if (!vt_mode) {
    // row-major [4096,1024] bf16
#pragma unroll
    for (int m = 0; m < 4; m++) {
#pragma unroll
      for (int n = 0; n < 4; n++) {
        const int col = col0 + n * 16 + qi;
#pragma unroll
        for (int r = 0; r < 4; r++) {
          const int row = row0 + m * 16 + g * 4 + r;
          out[(size_t)row * DM + col] = f2bf(acc[m][n][r] + bfv[n]);
        }
      }
    }
  } else {
    // V transposed per head: out[((b*NH+h)*DH+d)*SEQ + s]
#pragma unroll
    for (int m = 0; m < 4; m++) {
      const int s_base = row0 + m * 16 + g * 4;  // +r contiguous
      const int bb = s_base >> 11;
      const int s = s_base & (SEQ - 1);
#pragma unroll
      for (int n = 0; n < 4; n++) {
        const int col = col0 + n * 16 + qi;
        const int h = col >> 6, d = col & 63;
        ushort4 v;
        v.x = (unsigned short)f2bf(acc[m][n][0] + bfv[n]);
        v.y = (unsigned short)f2bf(acc[m][n][1] + bfv[n]);
        v.z = (unsigned short)f2bf(acc[m][n][2] + bfv[n]);
        v.w = (unsigned short)f2bf(acc[m][n][3] + bfv[n]);
        *(ushort4*)&out[(((size_t)bb * NH + h) * DH + d) * SEQ + s] = v;
      }
    }
  }
}

__global__ __launch_bounds__(256) void k_gemm_qkv(
    const float* __restrict__ q, const float* __restrict__ kv,
    const short* __restrict__ Wt, const float* __restrict__ bq,
    const float* __restrict__ bk, const float* __restrict__ bv,
    short* __restrict__ qm, short* __restrict__ km, short* __restrict__ vtb) {
  __shared__ short As[4096], Bs[4096];
  const int z = blockIdx.z;
  const float* X = (z == 0) ? q : kv;
  const short* W = Wt + (size_t)z * (DM * DM);
  const float* bias = (z == 0) ? bq : (z == 1) ? bk : bv;
  short* out = (z == 0) ? qm : (z == 1) ? km : vtb;
  gemm_body<1>(As, Bs, X, nullptr, W, bias, out, z == 2);
}

__global__ __launch_bounds__(256) void k_gemm_o(
    const short* __restrict__ attn, const short* __restrict__ Wto,
    const float* __restrict__ bo, short* __restrict__ om) {
  __shared__ short As[4096], Bs[4096];
  gemm_body<0>(As, Bs, nullptr, attn, Wto, bo, om, 0);
}

// ---------------------------------------------------------------- attention
// Swapped QK^T: S^T = K·Q^T (lane holds one q-column), online softmax per lane,
// PV as O^T = Vt·P^T. One wave = 16 q rows; block = 4 waves = 64 q rows.
__global__ __launch_bounds__(256) void k_attn(const short* __restrict__ qm,
                                              const short* __restrict__ km,
                                              const short* __restrict__ vt,
                                              short* __restrict__ attn) {
  const int bb = blockIdx.z, h = blockIdx.y;
  const int w = threadIdx.x >> 6, l = threadIdx.x & 63;
  const int g = l >> 4, qi = l & 15;
  const int q0 = blockIdx.x * 64 + w * 16;

  const short* Qp = qm + ((size_t)(bb * SEQ + q0 + qi)) * DM + h * DH;
  const short* Kp = km + ((size_t)(bb * SEQ)) * DM + h * DH;
  const short* Vp = vt + ((size_t)(bb * NH + h)) * DH * SEQ;

  const bf16x8 qb0 = *(const bf16x8*)(Qp + 8 * g);
  const bf16x8 qb1 = *(const bf16x8*)(Qp + 32 + 8 * g);

  float mrow = -1e30f, ssum = 0.f;
  f32x4 o[4];
#pragma unroll
  for (int f = 0; f < 4; f++) o[f] = (f32x4){0.f, 0.f, 0.f, 0.f};

  for (int kk0 = 0; kk0 < SEQ; kk0 += 32) {
    const short* Kb = Kp + (size_t)(kk0 + qi) * DM + 8 * g;
    const bf16x8 k00 = *(const bf16x8*)(Kb);
    const bf16x8 k01 = *(const bf16x8*)(Kb + 32);
    const bf16x8 k10 = *(const bf16x8*)(Kb + 16 * DM);
    const bf16x8 k11 = *(const bf16x8*)(Kb + 16 * DM + 32);

    f32x4 st0 = (f32x4){0.f, 0.f, 0.f, 0.f};
    f32x4 st1 = (f32x4){0.f, 0.f, 0.f, 0.f};
    st0 = __builtin_amdgcn_mfma_f32_16x16x32_bf16(k00, qb0, st0, 0, 0, 0);
    st0 = __builtin_amdgcn_mfma_f32_16x16x32_bf16(k01, qb1, st0, 0, 0, 0);
    st1 = __builtin_amdgcn_mfma_f32_16x16x32_bf16(k10, qb0, st1, 0, 0, 0);
    st1 = __builtin_amdgcn_mfma_f32_16x16x32_bf16(k11, qb1, st1, 0, 0, 0);

    float p[8];
#pragma unroll
    for (int r = 0; r < 4; r++) {
      p[r] = st0[r] * 0.125f;
      p[4 + r] = st1[r] * 0.125f;
    }
    float pmax = p[0];
#pragma unroll
    for (int i = 1; i < 8; i++) pmax = fmaxf(pmax, p[i]);
    pmax = fmaxf(pmax, __shfl_xor(pmax, 16));
    pmax = fmaxf(pmax, __shfl_xor(pmax, 32));
    const float mn = fmaxf(mrow, pmax);
    const float alpha = __expf(mrow - mn);
    mrow = mn;
    float psum = 0.f;
#pragma unroll
    for (int i = 0; i < 8; i++) {
      p[i] = __expf(p[i] - mn);
      psum += p[i];
    }
    ssum = ssum * alpha + psum;
#pragma unroll
    for (int f = 0; f < 4; f++) o[f] *= alpha;

    unsigned pk[4];
#pragma unroll
    for (int r = 0; r < 4; r++)
      pk[r] = (unsigned)(unsigned short)f2bf(p[r]) |
              ((unsigned)(unsigned short)f2bf(p[4 + r]) << 16);

    // redistribute P^T for PV B-operand: lane needs P[q][kk0+8g+j]
    bf16x8 pb;
#pragma unroll
    for (int j = 0; j < 8; j++) {
      const int src = qi + 16 * (((g & 1) << 1) + (j >> 2));
      const unsigned sh = (unsigned)__shfl((int)pk[j & 3], src, 64);
      const unsigned short hv =
          (g & 2) ? (unsigned short)(sh >> 16) : (unsigned short)(sh & 0xffffu);
      pb[j] = (short)hv;
    }

#pragma unroll
    for (int f = 0; f < 4; f++) {
      const bf16x8 aV =
          *(const bf16x8*)(Vp + (size_t)(f * 16 + qi) * SEQ + kk0 + 8 * g);
      o[f] = __builtin_amdgcn_mfma_f32_16x16x32_bf16(aV, pb, o[f], 0, 0, 0);
    }
  }

  float denom = ssum + __shfl_xor(ssum, 16);
  denom = denom + __shfl_xor(denom, 32);
  const float inv = 1.f / denom;

  short* Op = attn + ((size_t)(bb * SEQ + q0 + qi)) * DM + h * DH;
#pragma unroll
  for (int f = 0; f < 4; f++) {
    ushort4 v;
    v.x = (unsigned short)f2bf(o[f][0] * inv);
    v.y = (unsigned short)f2bf(o[f][1] * inv);
    v.z = (unsigned short)f2bf(o[f][2] * inv);
    v.w = (unsigned short)f2bf(o[f][3] * inv);
    *(ushort4*)(Op + f * 16 + g * 4) = v;
  }
}

// ---------------------------------------------------------------- layernorm
__global__ __launch_bounds__(256) void k_ln(const float* __restrict__ q,
                                            const short* __restrict__ om,
                                            const float* __restrict__ gamma,
                                            const float* __restrict__ beta,
                                            float* __restrict__ out) {
  const int row = blockIdx.x;
  const int t = threadIdx.x;
  const int w = t >> 6, l = t & 63;
  const size_t base = (size_t)row * DM + t * 4;
  const float4 qv = *(const float4*)(q + base);
  const ushort4 ov = *(const ushort4*)(om + base);
  float v[4];
  v[0] = qv.x + bf2f((short)ov.x);
  v[1] = qv.y + bf2f((short)ov.y);
  v[2] = qv.z + bf2f((short)ov.z);
  v[3] = qv.w + bf2f((short)ov.w);
  float s = v[0] + v[1] + v[2] + v[3];
  float s2 = v[0] * v[0] + v[1] * v[1] + v[2] * v[2] + v[3] * v[3];
#pragma unroll
  for (int off = 32; off >= 1; off >>= 1) {
    s += __shfl_xor(s, off);
    s2 += __shfl_xor(s2, off);
  }
  __shared__ float ps[4], ps2[4];
  if (l == 0) {
    ps[w] = s;
    ps2[w] = s2;
  }
  __syncthreads();
  const float St = ps[0] + ps[1] + ps[2] + ps[3];
  const float S2t = ps2[0] + ps2[1] + ps2[2] + ps2[3];
  const float mu = St * (1.f / 1024.f);
  float var = S2t * (1.f / 1024.f) - mu * mu;
  const float rstd = rsqrtf(var + 1e-5f);
  const float4 gv = *(const float4*)(gamma + t * 4);
  const float4 bv = *(const float4*)(beta + t * 4);
  float4 ovv;
  ovv.x = (v[0] - mu) * rstd * gv.x + bv.x;
  ovv.y = (v[1] - mu) * rstd * gv.y + bv.y;
  ovv.z = (v[2] - mu) * rstd * gv.z + bv.z;
  ovv.w = (v[3] - mu) * rstd * gv.w + bv.w;
  *(float4*)(out + base) = ovv;
}

// ---------------------------------------------------------------- launch
extern "C" void kernel_launch(void* const* d_in, const int* in_sizes, int n_in,
                              void* d_out, int out_size, void* d_ws, size_t ws_size,
                              hipStream_t stream) {
  const float* q = (const float*)d_in[0];
  const float* kv = (const float*)d_in[1];
  const float* Wq = (const float*)d_in[2];
  const float* bq = (const float*)d_in[3];
  const float* Wk = (const float*)d_in[4];
  const float* bk = (const float*)d_in[5];
  const float* Wv = (const float*)d_in[6];
  const float* bv = (const float*)d_in[7];
  const float* Wo = (const float*)d_in[8];
  const float* bo = (const float*)d_in[9];
  const float* gamma = (const float*)d_in[10];
  const float* beta = (const float*)d_in[11];

  short* ws = (short*)d_ws;
  short* Wt = ws;                       // 4 * 1Mi elems (Wq^T,Wk^T,Wv^T,Wo^T)
  short* qm = ws + 4u * 1048576u;       // [4096,1024] bf16
  short* km = qm + 4194304u;            // [4096,1024] bf16
  short* vtb = km + 4194304u;           // [B,H,64,S] bf16
  short* attn = vtb + 4194304u;         // [4096,1024] bf16
  short* om = attn + 4194304u;          // [4096,1024] bf16

  hipLaunchKernelGGL(k_transpose, dim3(32, 32, 4), dim3(32, 8), 0, stream,
                     Wq, Wk, Wv, Wo, Wt);
  hipLaunchKernelGGL(k_gemm_qkv, dim3(8, 32, 3), dim3(256), 0, stream,
                     q, kv, Wt, bq, bk, bv, qm, km, vtb);
  hipLaunchKernelGGL(k_attn, dim3(32, 16, 2), dim3(256), 0, stream,
                     qm, km, vtb, attn);
  hipLaunchKernelGGL(k_gemm_o, dim3(8, 32, 1), dim3(256), 0, stream,
                     attn, Wt + 3u * 1048576u, bo, om);
  hipLaunchKernelGGL(k_ln, dim3(4096), dim3(256), 0, stream,
                     q, om, gamma, beta, (float*)d_out);
}